// Round 18
// baseline (239.082 us; speedup 1.0000x reference)
//
#include <hip/hip_runtime.h>
#include <hip/hip_bf16.h>

typedef _Float16 half8 __attribute__((ext_vector_type(8)));
typedef _Float16 half4 __attribute__((ext_vector_type(4)));
typedef float f32x4 __attribute__((ext_vector_type(4)));

#define KDIM 1024
#define NDIM 1024
#define MROWS 16384   // B*L = 4*4096

#define GLD_LDS16(g, l)                                                  \
  __builtin_amdgcn_global_load_lds(                                      \
      (const __attribute__((address_space(1))) void*)(g),                \
      (__attribute__((address_space(3))) void*)(l), 16, 0, 0)

// ---------------------------------------------------------------------------
// fp32 -> fp16 convert (standalone, only for k; r13 2048-block shape)
// ---------------------------------------------------------------------------
__global__ __launch_bounds__(256)
void cvt_f32_to_f16(const float* __restrict__ src, _Float16* __restrict__ dst,
                    int n8) {
  for (int i = blockIdx.x * 256 + threadIdx.x; i < n8; i += gridDim.x * 256) {
    float4 f0 = ((const float4*)src)[2 * i];
    float4 f1 = ((const float4*)src)[2 * i + 1];
    half8 h;
    h[0] = (_Float16)f0.x; h[1] = (_Float16)f0.y;
    h[2] = (_Float16)f0.z; h[3] = (_Float16)f0.w;
    h[4] = (_Float16)f1.x; h[5] = (_Float16)f1.y;
    h[6] = (_Float16)f1.z; h[7] = (_Float16)f1.w;
    ((half8*)dst)[i] = h;
  }
}

__global__ __launch_bounds__(256)
void cvt_w(const float* __restrict__ s0, _Float16* __restrict__ d0,
           const float* __restrict__ s1, _Float16* __restrict__ d1,
           const float* __restrict__ s2, _Float16* __restrict__ d2,
           const float* __restrict__ s3, _Float16* __restrict__ d3) {
  const float* src;
  _Float16* dst;
  switch (blockIdx.y) {
    case 0: src = s0; dst = d0; break;
    case 1: src = s1; dst = d1; break;
    case 2: src = s2; dst = d2; break;
    default: src = s3; dst = d3; break;
  }
  size_t i = (size_t)blockIdx.x * 256 + threadIdx.x;
  float4 f = ((const float4*)src)[i];
  half4 h;
  h[0] = (_Float16)f.x; h[1] = (_Float16)f.y;
  h[2] = (_Float16)f.z; h[3] = (_Float16)f.w;
  ((half4*)dst)[i] = h;
}

// ---------------------------------------------------------------------------
// 8-PHASE 256x256 GEMM (r14-r17 verified main loop).
// MODE: 0 natural, 1 per-head transposed fp16, 2 fused attn epilogue
//       (per-wave-private Ct, r16: bank conflicts = 0).
// CVT=1 (r18): convert tail with 4x ILP — 4 chunks/outer-iter, all 8
// float4 loads issued before the 4 half8 stores (r17's 2-in-flight tail
// measured 2.5 TB/s; limiter is outstanding loads). n8 = 16*stride exactly.
// ---------------------------------------------------------------------------
template <int ACT, int MODE, int CVT, typename TOUT>
__global__ __launch_bounds__(512, 2)
void gemm_8ph(const _Float16* __restrict__ X, const _Float16* __restrict__ W,
              const float* __restrict__ bias, TOUT* __restrict__ Y,
              const _Float16* __restrict__ KVTx,
              const float* __restrict__ csrc, _Float16* __restrict__ cdst) {
  __shared__ char smem[131072];
  _Float16* As = (_Float16*)smem;             // 64 KB
  _Float16* Bs = (_Float16*)(smem + 65536);   // 64 KB

  const int tid  = threadIdx.x;
  const int lane = tid & 63;
  const int w    = tid >> 6;        // 0..7
  const int wm   = w >> 2;          // 0..1 -> rows wm*128
  const int wn   = w & 3;           // 0..3 -> cols wn*64

  const int bid = blockIdx.x;
  const int wid = (bid & 7) * 32 + (bid >> 3);   // 256 blocks, bijective
  const int m0  = (wid >> 2) * 256;
  const int n0  = (wid & 3) * 256;

  const int srow = lane >> 2;
  const int gsl  = (lane & 3) ^ ((lane >> 3) & 3);
  const _Float16* gA = X + (size_t)(m0 + w * 32 + srow) * KDIM + gsl * 8;
  const _Float16* gB = W + (size_t)(n0 + w * 32 + srow) * KDIM + gsl * 8;

#define STG(OPD, GSRC, T, KH, D)                                             \
  {                                                                          \
    _Float16* ldst = OPD + ((D) * 2 + (KH)) * 8192 + (w * 32) * 32;          \
    const _Float16* gs = GSRC + (size_t)(T) * 64 + (KH) * 32;                \
    GLD_LDS16(gs, ldst);                                                     \
    GLD_LDS16(gs + (size_t)16 * KDIM, ldst + 16 * 32);                       \
  }

  const int rsl = ((lane >> 4) ^ ((lane >> 1) & 3)) << 4;

#define RDA(DST, D, KH, MH)                                                  \
  _Pragma("unroll") for (int mi = 0; mi < 4; ++mi) {                         \
    int r = wm * 128 + (MH) * 64 + mi * 16 + (lane & 15);                    \
    DST[mi] = *(const half8*)((const char*)As + ((D) * 2 + (KH)) * 16384 +   \
                              r * 64 + rsl);                                 \
  }
#define RDB(D, KH)                                                           \
  _Pragma("unroll") for (int ni = 0; ni < 4; ++ni) {                         \
    int r = wn * 64 + ni * 16 + (lane & 15);                                 \
    b[ni] = *(const half8*)((const char*)Bs + ((D) * 2 + (KH)) * 16384 +     \
                            r * 64 + rsl);                                   \
  }
#define MM(AV, MH)                                                           \
  __builtin_amdgcn_s_setprio(1);                                             \
  _Pragma("unroll") for (int mi = 0; mi < 4; ++mi)                           \
    _Pragma("unroll") for (int ni = 0; ni < 4; ++ni)                         \
      acc[(MH) * 4 + mi][ni] = __builtin_amdgcn_mfma_f32_16x16x32_f16(       \
          AV[mi], b[ni], acc[(MH) * 4 + mi][ni], 0, 0, 0);                   \
  __builtin_amdgcn_s_setprio(0);

  f32x4 acc[8][4] = {};
  half8 a0[4], a1[4], b[4];

  // prologue: tile 0 halves [A-kh0, B-kh0, A-kh1, B-kh1] -> dbuf 0
  STG(As, gA, 0, 0, 0); STG(Bs, gB, 0, 0, 0);
  STG(As, gA, 0, 1, 0); STG(Bs, gB, 0, 1, 0);

  for (int T = 0; T < 16; ++T) {
    const int d = T & 1, e = d ^ 1;
    // ---- p0: kh0, m-half0
    asm volatile("s_waitcnt vmcnt(4)" ::: "memory");
    asm volatile("s_barrier" ::: "memory");
    RDA(a0, d, 0, 0);
    RDB(d, 0);
    if (T < 15) STG(As, gA, T + 1, 0, e);
    MM(a0, 0);
    // ---- p1: kh0, m-half1
    RDA(a1, d, 0, 1);
    if (T < 15) STG(Bs, gB, T + 1, 0, e);
    MM(a1, 1);
    // ---- p2: kh1, m-half0
    if (T < 15) { asm volatile("s_waitcnt vmcnt(4)" ::: "memory"); }
    else        { asm volatile("s_waitcnt vmcnt(0)" ::: "memory"); }
    asm volatile("s_barrier" ::: "memory");
    RDA(a0, d, 1, 0);
    RDB(d, 1);
    if (T < 15) STG(As, gA, T + 1, 1, e);
    MM(a0, 0);
    // ---- p3: kh1, m-half1
    RDA(a1, d, 1, 1);
    if (T < 15) STG(Bs, gB, T + 1, 1, e);
    MM(a1, 1);
  }
#undef STG
#undef RDA
#undef RDB
#undef MM

  if constexpr (MODE == 2) {
    // ---- fused linear-attention epilogue (per-wave-private Ct, r16) -----
    __syncthreads();   // all waves done reading staging LDS
    _Float16* Cw = (_Float16*)(smem + w * 16384);   // wave-private 16KB
#pragma unroll
    for (int ni = 0; ni < 4; ++ni) {
      int dcol = ni * 16 + (lane & 15);          // d within head, 0..63
      float bv = bias[n0 + wn * 64 + dcol];
#pragma unroll
      for (int mi = 0; mi < 8; ++mi) {
#pragma unroll
        for (int i = 0; i < 4; ++i) {
          int rowr = mi * 16 + ((lane >> 4) << 2) + i;   // 0..127
          float v = acc[mi][ni][i] + bv;
          v = (v > 0.f) ? (v + 1.f) : __expf(v);
          int byte = rowr * 128 + dcol * 2;
          byte ^= (rowr & 7) << 4;
          *(_Float16*)((char*)Cw + byte) = (_Float16)v;
        }
      }
    }
    asm volatile("s_waitcnt lgkmcnt(0)" ::: "memory");
    __builtin_amdgcn_sched_barrier(0);
    const int bh0 = ((m0 >> 12) << 4) + (n0 >> 6);
    const _Float16* kvp = KVTx + (size_t)(bh0 + wn) * 5120;
#pragma unroll
    for (int half = 0; half < 2; ++half) {
      f32x4 acc2[4][5] = {};
#pragma unroll
      for (int kk = 0; kk < 2; ++kk) {
        half8 afr2[4], bfr2[5];
#pragma unroll
        for (int m = 0; m < 4; ++m) {
          int rowr = half * 64 + m * 16 + (lane & 15);
          int byte = rowr * 128 + kk * 64 + ((lane >> 4) << 4);
          byte ^= (rowr & 7) << 4;
          afr2[m] = *(const half8*)((const char*)Cw + byte);
        }
#pragma unroll
        for (int n = 0; n < 5; ++n) {
          int row = n * 16 + (lane & 15);
          bfr2[n] = *(const half8*)(kvp + row * 64 + kk * 32 + ((lane >> 4) << 3));
        }
#pragma unroll
        for (int m = 0; m < 4; ++m)
#pragma unroll
          for (int n = 0; n < 5; ++n)
            acc2[m][n] = __builtin_amdgcn_mfma_f32_16x16x32_f16(
                afr2[m], bfr2[n], acc2[m][n], 0, 0, 0);
      }
#pragma unroll
      for (int m = 0; m < 4; ++m) {
#pragma unroll
        for (int i = 0; i < 4; ++i) {
          float dn = __shfl(acc2[m][4][i], lane & 48);
          float z  = 1.f / (dn + 1e-6f);
          size_t row = (size_t)m0 + wm * 128 + half * 64 + m * 16 +
                       ((lane >> 4) << 2) + i;
#pragma unroll
          for (int n = 0; n < 4; ++n) {
            int col = n0 + wn * 64 + n * 16 + (lane & 15);
            Y[row * NDIM + col] = (TOUT)(acc2[m][n][i] * z);
          }
        }
      }
    }
    return;
  }

  // ---- MODE 0/1 epilogues
#pragma unroll
  for (int ni = 0; ni < 4; ++ni) {
    int col  = n0 + wn * 64 + ni * 16 + (lane & 15);
    float bv = bias[col];
#pragma unroll
    for (int mi = 0; mi < 8; ++mi) {
      int r0 = m0 + wm * 128 + mi * 16 + ((lane >> 4) << 2);
      if constexpr (MODE == 1) {
        int bb = r0 >> 12;
        int l0 = r0 & 4095;
        half4 hv;
#pragma unroll
        for (int i = 0; i < 4; ++i) {
          float v = acc[mi][ni][i] + bv;
          if constexpr (ACT == 1) v = (v > 0.f) ? (v + 1.f) : __expf(v);
          hv[i] = (_Float16)v;
        }
        *(half4*)((_Float16*)Y + ((size_t)(bb * 1024 + col)) * 4096 + l0) = hv;
      } else {
#pragma unroll
        for (int i = 0; i < 4; ++i) {
          float v = acc[mi][ni][i] + bv;
          if constexpr (ACT == 1) v = (v > 0.f) ? (v + 1.f) : __expf(v);
          Y[(size_t)(r0 + i) * NDIM + col] = (TOUT)v;
        }
      }
    }
  }

  // ---- CVT tail (4x ILP): 4 chunks per outer iter, 8 loads then 4 stores
  if constexpr (CVT) {
    const int n8 = MROWS * KDIM / 8;        // 2,097,152 = 16 * stride
    const int stride = 256 * 512;
    const int i0 = bid * 512 + tid;
    for (int i = i0; i < n8; i += 4 * stride) {
      float4 f[8];
#pragma unroll
      for (int u = 0; u < 4; ++u) {
        f[2 * u]     = ((const float4*)csrc)[2 * (i + u * stride)];
        f[2 * u + 1] = ((const float4*)csrc)[2 * (i + u * stride) + 1];
      }
#pragma unroll
      for (int u = 0; u < 4; ++u) {
        half8 h;
        h[0] = (_Float16)f[2 * u].x;     h[1] = (_Float16)f[2 * u].y;
        h[2] = (_Float16)f[2 * u].z;     h[3] = (_Float16)f[2 * u].w;
        h[4] = (_Float16)f[2 * u + 1].x; h[5] = (_Float16)f[2 * u + 1].y;
        h[6] = (_Float16)f[2 * u + 1].z; h[7] = (_Float16)f[2 * u + 1].w;
        ((half8*)cdst)[i + u * stride] = h;
      }
    }
  }
}

// ---------------------------------------------------------------------------
// kv_mfma: per (bh, chunk of 1024 l): partial C'[e][d] = sum_l VT[e][l]*KT[d][l]
// A = VT rows + synthesized ones-row (m-frag 4 -> Ksum); B = KT rows.
// ---------------------------------------------------------------------------
__global__ __launch_bounds__(256, 2)
void kv_mfma(const _Float16* __restrict__ KT, const _Float16* __restrict__ VT,
             _Float16* __restrict__ pKV) {
  const int bh = blockIdx.x;      // 0..63
  const int ch = blockIdx.y;      // 0..3
  const int tid  = threadIdx.x;
  const int lane = tid & 63;
  const int w    = tid >> 6;

  __shared__ _Float16 As[64 * 64];
  __shared__ _Float16 Bs[64 * 64];

  const int lr = lane >> 3;
  const int ls = (lane & 7) ^ lr;
  const size_t lbase = (size_t)ch * 1024 + ls * 8;
  const _Float16* gA = VT + (size_t)(bh * 64 + w * 16 + lr) * 4096 + lbase;
  const _Float16* gB = KT + (size_t)(bh * 64 + w * 16 + lr) * 4096 + lbase;
  _Float16* ldsA = As + (w * 16) * 64;
  _Float16* ldsB = Bs + (w * 16) * 64;

  half8 aones;
#pragma unroll
  for (int j = 0; j < 8; ++j) aones[j] = (lane & 15) == 0 ? (_Float16)1.0f : (_Float16)0.0f;

  f32x4 acc[5] = {};

  for (int k0 = 0; k0 < 1024; k0 += 64) {
    __syncthreads();
#pragma unroll
    for (int c = 0; c < 2; ++c) {
      GLD_LDS16(gA + k0 + (size_t)(c * 8) * 4096, ldsA + c * 8 * 64);
      GLD_LDS16(gB + k0 + (size_t)(c * 8) * 4096, ldsB + c * 8 * 64);
    }
    __syncthreads();

    half8 afr[4][2], bfr[2];
#pragma unroll
    for (int m = 0; m < 4; ++m)
#pragma unroll
      for (int kk = 0; kk < 2; ++kk) {
        int row  = m * 16 + (lane & 15);
        int byte = row * 128 + ((lane >> 4) << 4) + kk * 64;
        byte ^= (row & 7) << 4;
        afr[m][kk] = *(const half8*)((const char*)As + byte);
      }
#pragma unroll
    for (int kk = 0; kk < 2; ++kk) {
      int row  = w * 16 + (lane & 15);
      int byte = row * 128 + ((lane >> 4) << 4) + kk * 64;
      byte ^= (row & 7) << 4;
      bfr[kk] = *(const half8*)((const char*)Bs + byte);
    }
#pragma unroll
    for (int kk = 0; kk < 2; ++kk) {
#pragma unroll
      for (int m = 0; m < 4; ++m)
        acc[m] = __builtin_amdgcn_mfma_f32_16x16x32_f16(afr[m][kk], bfr[kk],
                                                        acc[m], 0, 0, 0);
      acc[4] = __builtin_amdgcn_mfma_f32_16x16x32_f16(aones, bfr[kk],
                                                      acc[4], 0, 0, 0);
    }
  }

  _Float16* outp = pKV + ((size_t)ch * 64 + bh) * 5120;
  const int col = w * 16 + (lane & 15);
#pragma unroll
  for (int m = 0; m < 5; ++m) {
#pragma unroll
    for (int i = 0; i < 4; ++i) {
      int row = m * 16 + ((lane >> 4) << 2) + i;
      outp[row * 64 + col] = (_Float16)acc[m][i];
    }
  }
}

// ---------------------------------------------------------------------------
__global__ __launch_bounds__(256)
void kv_combine(const _Float16* __restrict__ pKV, _Float16* __restrict__ KVTx) {
  int g = blockIdx.x * 256 + threadIdx.x;   // 0..327679
  int bh = g / 5120;
  int j  = g - bh * 5120;
  float s = 0.f;
#pragma unroll
  for (int ch = 0; ch < 4; ++ch)
    s += (float)pKV[((size_t)ch * 64 + bh) * 5120 + j];
  KVTx[(size_t)bh * 5120 + j] = (_Float16)s;
}

// ---------------------------------------------------------------------------
extern "C" void kernel_launch(void* const* d_in, const int* in_sizes, int n_in,
                              void* d_out, int out_size, void* d_ws, size_t ws_size,
                              hipStream_t stream) {
  const float* q  = (const float*)d_in[0];
  const float* k  = (const float*)d_in[1];
  const float* v  = (const float*)d_in[2];
  const float* wq = (const float*)d_in[3];
  const float* bq = (const float*)d_in[4];
  const float* wk = (const float*)d_in[5];
  const float* bk = (const float*)d_in[6];
  const float* wv = (const float*)d_in[7];
  const float* bv = (const float*)d_in[8];
  const float* wo = (const float*)d_in[9];
  const float* bo = (const float*)d_in[10];
  float* out = (float*)d_out;

  char* ws = (char*)d_ws;
  _Float16* Xk   = (_Float16*)(ws);                      // 0..32MB
  _Float16* KT   = (_Float16*)(ws + 33554432);           // 32..64MB
  _Float16* VT   = (_Float16*)(ws + 67108864);           // 64..96MB
  _Float16* pKV  = (_Float16*)(ws + 100663296);          // 2.62MB over whk/whv
  _Float16* whk  = (_Float16*)(ws + 100663296);          // 2MB (dies after K-gemm)
  _Float16* whv  = (_Float16*)(ws + 102760448);          // 2MB (dies after V-gemm)
  _Float16* whq  = (_Float16*)(ws + 104857600);          // 2MB
  _Float16* who  = (_Float16*)(ws + 106954752);          // 2MB (lives to the end)
  _Float16* KVTx = (_Float16*)(ws + 109051904);          // 655KB
  _Float16* att  = KT;                                   // reuse KT after KV built
  // d_out (64MB) as scratch until the final GEMM:
  _Float16* Xv   = (_Float16*)d_out;                     // 0..32MB of d_out
  _Float16* Xq   = (_Float16*)((char*)d_out + 33554432); // 32..64MB of d_out

  const int N8_BIG = MROWS * KDIM / 8;             // 2,097,152
  const int GBLK8  = (MROWS / 256) * (NDIM / 256); // 256 blocks

  // weights (fused small): 262,144 f4 -> (1024,4)
  cvt_w<<<dim3(1024, 4), 256, 0, stream>>>(wq, whq, wk, whk, wv, whv, wo, who);

  // k convert (standalone — nothing to overlap with; r13 2048-block shape)
  cvt_f32_to_f16<<<2048, 256, 0, stream>>>(k, Xk, N8_BIG);

  // K projection + fused v-convert tail (4x-ILP tail)
  gemm_8ph<1, 1, 1, _Float16><<<GBLK8, 512, 0, stream>>>(
      Xk, whk, bk, KT, nullptr, v, Xv);
  // V projection + fused q-convert tail
  gemm_8ph<0, 1, 1, _Float16><<<GBLK8, 512, 0, stream>>>(
      Xv, whv, bv, VT, nullptr, q, Xq);

  kv_mfma<<<dim3(64, 4), 256, 0, stream>>>(KT, VT, pKV);
  kv_combine<<<1280, 256, 0, stream>>>(pKV, KVTx);

  // Q projection + attention fused (8-phase + per-wave Ct epilogue)
  gemm_8ph<1, 2, 0, _Float16><<<GBLK8, 512, 0, stream>>>(
      Xq, whq, bq, att, KVTx, nullptr, nullptr);

  // output projection (8-phase, natural fp32) -> d_out (Xv/Xq dead)
  gemm_8ph<0, 0, 0, float><<<GBLK8, 512, 0, stream>>>(
      att, who, bo, out, nullptr, nullptr, nullptr);
}

// Round 19
// 237.541 us; speedup vs baseline: 1.0065x; 1.0065x over previous
//
#include <hip/hip_runtime.h>
#include <hip/hip_bf16.h>

typedef _Float16 half8 __attribute__((ext_vector_type(8)));
typedef _Float16 half4 __attribute__((ext_vector_type(4)));
typedef float f32x4 __attribute__((ext_vector_type(4)));

#define KDIM 1024
#define NDIM 1024
#define MROWS 16384   // B*L = 4*4096

#define GLD_LDS16(g, l)                                                  \
  __builtin_amdgcn_global_load_lds(                                      \
      (const __attribute__((address_space(1))) void*)(g),                \
      (__attribute__((address_space(3))) void*)(l), 16, 0, 0)

// ---------------------------------------------------------------------------
// fp32 -> fp16 convert (standalone, only for k)
// ---------------------------------------------------------------------------
__global__ __launch_bounds__(256)
void cvt_f32_to_f16(const float* __restrict__ src, _Float16* __restrict__ dst,
                    int n8) {
  for (int i = blockIdx.x * 256 + threadIdx.x; i < n8; i += gridDim.x * 256) {
    float4 f0 = ((const float4*)src)[2 * i];
    float4 f1 = ((const float4*)src)[2 * i + 1];
    half8 h;
    h[0] = (_Float16)f0.x; h[1] = (_Float16)f0.y;
    h[2] = (_Float16)f0.z; h[3] = (_Float16)f0.w;
    h[4] = (_Float16)f1.x; h[5] = (_Float16)f1.y;
    h[6] = (_Float16)f1.z; h[7] = (_Float16)f1.w;
    ((half8*)dst)[i] = h;
  }
}

__global__ __launch_bounds__(256)
void cvt_w(const float* __restrict__ s0, _Float16* __restrict__ d0,
           const float* __restrict__ s1, _Float16* __restrict__ d1,
           const float* __restrict__ s2, _Float16* __restrict__ d2,
           const float* __restrict__ s3, _Float16* __restrict__ d3) {
  const float* src;
  _Float16* dst;
  switch (blockIdx.y) {
    case 0: src = s0; dst = d0; break;
    case 1: src = s1; dst = d1; break;
    case 2: src = s2; dst = d2; break;
    default: src = s3; dst = d3; break;
  }
  size_t i = (size_t)blockIdx.x * 256 + threadIdx.x;
  float4 f = ((const float4*)src)[i];
  half4 h;
  h[0] = (_Float16)f.x; h[1] = (_Float16)f.y;
  h[2] = (_Float16)f.z; h[3] = (_Float16)f.w;
  ((half4*)dst)[i] = h;
}

// ---------------------------------------------------------------------------
// 8-PHASE 256x256 GEMM (r14/r15/r16-verified main loop).
// MODE: 0 natural, 1 per-head transposed fp16, 2 fused attn epilogue
//       (per-wave-private Ct, r16-verified: bank conflicts = 0).
// CVT: 1 = grid-stride fp32->fp16 convert TAIL (csrc -> cdst). Deletes a
// dispatch boundary; output consumed only by the NEXT dispatch -> race-free.
// ---------------------------------------------------------------------------
template <int ACT, int MODE, int CVT, typename TOUT>
__global__ __launch_bounds__(512, 2)
void gemm_8ph(const _Float16* __restrict__ X, const _Float16* __restrict__ W,
              const float* __restrict__ bias, TOUT* __restrict__ Y,
              const _Float16* __restrict__ KVTx,
              const float* __restrict__ csrc, _Float16* __restrict__ cdst) {
  __shared__ char smem[131072];
  _Float16* As = (_Float16*)smem;             // 64 KB
  _Float16* Bs = (_Float16*)(smem + 65536);   // 64 KB

  const int tid  = threadIdx.x;
  const int lane = tid & 63;
  const int w    = tid >> 6;        // 0..7
  const int wm   = w >> 2;          // 0..1 -> rows wm*128
  const int wn   = w & 3;           // 0..3 -> cols wn*64

  const int bid = blockIdx.x;
  const int wid = (bid & 7) * 32 + (bid >> 3);   // 256 blocks, bijective
  const int m0  = (wid >> 2) * 256;
  const int n0  = (wid & 3) * 256;

  const int srow = lane >> 2;
  const int gsl  = (lane & 3) ^ ((lane >> 3) & 3);
  const _Float16* gA = X + (size_t)(m0 + w * 32 + srow) * KDIM + gsl * 8;
  const _Float16* gB = W + (size_t)(n0 + w * 32 + srow) * KDIM + gsl * 8;

#define STG(OPD, GSRC, T, KH, D)                                             \
  {                                                                          \
    _Float16* ldst = OPD + ((D) * 2 + (KH)) * 8192 + (w * 32) * 32;          \
    const _Float16* gs = GSRC + (size_t)(T) * 64 + (KH) * 32;                \
    GLD_LDS16(gs, ldst);                                                     \
    GLD_LDS16(gs + (size_t)16 * KDIM, ldst + 16 * 32);                       \
  }

  const int rsl = ((lane >> 4) ^ ((lane >> 1) & 3)) << 4;

#define RDA(DST, D, KH, MH)                                                  \
  _Pragma("unroll") for (int mi = 0; mi < 4; ++mi) {                         \
    int r = wm * 128 + (MH) * 64 + mi * 16 + (lane & 15);                    \
    DST[mi] = *(const half8*)((const char*)As + ((D) * 2 + (KH)) * 16384 +   \
                              r * 64 + rsl);                                 \
  }
#define RDB(D, KH)                                                           \
  _Pragma("unroll") for (int ni = 0; ni < 4; ++ni) {                         \
    int r = wn * 64 + ni * 16 + (lane & 15);                                 \
    b[ni] = *(const half8*)((const char*)Bs + ((D) * 2 + (KH)) * 16384 +     \
                            r * 64 + rsl);                                   \
  }
#define MM(AV, MH)                                                           \
  __builtin_amdgcn_s_setprio(1);                                             \
  _Pragma("unroll") for (int mi = 0; mi < 4; ++mi)                           \
    _Pragma("unroll") for (int ni = 0; ni < 4; ++ni)                         \
      acc[(MH) * 4 + mi][ni] = __builtin_amdgcn_mfma_f32_16x16x32_f16(       \
          AV[mi], b[ni], acc[(MH) * 4 + mi][ni], 0, 0, 0);                   \
  __builtin_amdgcn_s_setprio(0);

  f32x4 acc[8][4] = {};
  half8 a0[4], a1[4], b[4];

  // prologue: tile 0 halves [A-kh0, B-kh0, A-kh1, B-kh1] -> dbuf 0
  STG(As, gA, 0, 0, 0); STG(Bs, gB, 0, 0, 0);
  STG(As, gA, 0, 1, 0); STG(Bs, gB, 0, 1, 0);

  for (int T = 0; T < 16; ++T) {
    const int d = T & 1, e = d ^ 1;
    // ---- p0: kh0, m-half0
    asm volatile("s_waitcnt vmcnt(4)" ::: "memory");
    asm volatile("s_barrier" ::: "memory");
    RDA(a0, d, 0, 0);
    RDB(d, 0);
    if (T < 15) STG(As, gA, T + 1, 0, e);
    MM(a0, 0);
    // ---- p1: kh0, m-half1
    RDA(a1, d, 0, 1);
    if (T < 15) STG(Bs, gB, T + 1, 0, e);
    MM(a1, 1);
    // ---- p2: kh1, m-half0
    if (T < 15) { asm volatile("s_waitcnt vmcnt(4)" ::: "memory"); }
    else        { asm volatile("s_waitcnt vmcnt(0)" ::: "memory"); }
    asm volatile("s_barrier" ::: "memory");
    RDA(a0, d, 1, 0);
    RDB(d, 1);
    if (T < 15) STG(As, gA, T + 1, 1, e);
    MM(a0, 0);
    // ---- p3: kh1, m-half1
    RDA(a1, d, 1, 1);
    if (T < 15) STG(Bs, gB, T + 1, 1, e);
    MM(a1, 1);
  }
#undef STG
#undef RDA
#undef RDB
#undef MM

  if constexpr (MODE == 2) {
    // ---- fused linear-attention epilogue (per-wave-private Ct, r16) -----
    __syncthreads();   // all waves done reading staging LDS
    _Float16* Cw = (_Float16*)(smem + w * 16384);   // wave-private 16KB
#pragma unroll
    for (int ni = 0; ni < 4; ++ni) {
      int dcol = ni * 16 + (lane & 15);          // d within head, 0..63
      float bv = bias[n0 + wn * 64 + dcol];
#pragma unroll
      for (int mi = 0; mi < 8; ++mi) {
#pragma unroll
        for (int i = 0; i < 4; ++i) {
          int rowr = mi * 16 + ((lane >> 4) << 2) + i;   // 0..127
          float v = acc[mi][ni][i] + bv;
          v = (v > 0.f) ? (v + 1.f) : __expf(v);
          int byte = rowr * 128 + dcol * 2;
          byte ^= (rowr & 7) << 4;
          *(_Float16*)((char*)Cw + byte) = (_Float16)v;
        }
      }
    }
    asm volatile("s_waitcnt lgkmcnt(0)" ::: "memory");
    __builtin_amdgcn_sched_barrier(0);
    const int bh0 = ((m0 >> 12) << 4) + (n0 >> 6);
    const _Float16* kvp = KVTx + (size_t)(bh0 + wn) * 5120;
#pragma unroll
    for (int half = 0; half < 2; ++half) {
      f32x4 acc2[4][5] = {};
#pragma unroll
      for (int kk = 0; kk < 2; ++kk) {
        half8 afr2[4], bfr2[5];
#pragma unroll
        for (int m = 0; m < 4; ++m) {
          int rowr = half * 64 + m * 16 + (lane & 15);
          int byte = rowr * 128 + kk * 64 + ((lane >> 4) << 4);
          byte ^= (rowr & 7) << 4;
          afr2[m] = *(const half8*)((const char*)Cw + byte);
        }
#pragma unroll
        for (int n = 0; n < 5; ++n) {
          int row = n * 16 + (lane & 15);
          bfr2[n] = *(const half8*)(kvp + row * 64 + kk * 32 + ((lane >> 4) << 3));
        }
#pragma unroll
        for (int m = 0; m < 4; ++m)
#pragma unroll
          for (int n = 0; n < 5; ++n)
            acc2[m][n] = __builtin_amdgcn_mfma_f32_16x16x32_f16(
                afr2[m], bfr2[n], acc2[m][n], 0, 0, 0);
      }
#pragma unroll
      for (int m = 0; m < 4; ++m) {
#pragma unroll
        for (int i = 0; i < 4; ++i) {
          float dn = __shfl(acc2[m][4][i], lane & 48);
          float z  = 1.f / (dn + 1e-6f);
          size_t row = (size_t)m0 + wm * 128 + half * 64 + m * 16 +
                       ((lane >> 4) << 2) + i;
#pragma unroll
          for (int n = 0; n < 4; ++n) {
            int col = n0 + wn * 64 + n * 16 + (lane & 15);
            Y[row * NDIM + col] = (TOUT)(acc2[m][n][i] * z);
          }
        }
      }
    }
    return;
  }

  // ---- MODE 0/1 epilogues
#pragma unroll
  for (int ni = 0; ni < 4; ++ni) {
    int col  = n0 + wn * 64 + ni * 16 + (lane & 15);
    float bv = bias[col];
#pragma unroll
    for (int mi = 0; mi < 8; ++mi) {
      int r0 = m0 + wm * 128 + mi * 16 + ((lane >> 4) << 2);
      if constexpr (MODE == 1) {
        int bb = r0 >> 12;
        int l0 = r0 & 4095;
        half4 hv;
#pragma unroll
        for (int i = 0; i < 4; ++i) {
          float v = acc[mi][ni][i] + bv;
          if constexpr (ACT == 1) v = (v > 0.f) ? (v + 1.f) : __expf(v);
          hv[i] = (_Float16)v;
        }
        *(half4*)((_Float16*)Y + ((size_t)(bb * 1024 + col)) * 4096 + l0) = hv;
      } else {
#pragma unroll
        for (int i = 0; i < 4; ++i) {
          float v = acc[mi][ni][i] + bv;
          if constexpr (ACT == 1) v = (v > 0.f) ? (v + 1.f) : __expf(v);
          Y[(size_t)(r0 + i) * NDIM + col] = (TOUT)v;
        }
      }
    }
  }

  // ---- CVT tail: convert next projection's input (dispatch-fused)
  if constexpr (CVT) {
    const int n8 = MROWS * KDIM / 8;   // 2,097,152
    for (int i = bid * 512 + tid; i < n8; i += 256 * 512) {
      float4 f0 = ((const float4*)csrc)[2 * i];
      float4 f1 = ((const float4*)csrc)[2 * i + 1];
      half8 h;
      h[0] = (_Float16)f0.x; h[1] = (_Float16)f0.y;
      h[2] = (_Float16)f0.z; h[3] = (_Float16)f0.w;
      h[4] = (_Float16)f1.x; h[5] = (_Float16)f1.y;
      h[6] = (_Float16)f1.z; h[7] = (_Float16)f1.w;
      ((half8*)cdst)[i] = h;
    }
  }
}

// ---------------------------------------------------------------------------
// kv_mfma: per (bh, chunk of 1024 l): partial C'[e][d] = sum_l VT[e][l]*KT[d][l]
// A = VT rows + synthesized ones-row (m-frag 4 -> Ksum); B = KT rows.
// ---------------------------------------------------------------------------
__global__ __launch_bounds__(256, 2)
void kv_mfma(const _Float16* __restrict__ KT, const _Float16* __restrict__ VT,
             _Float16* __restrict__ pKV) {
  const int bh = blockIdx.x;      // 0..63
  const int ch = blockIdx.y;      // 0..3
  const int tid  = threadIdx.x;
  const int lane = tid & 63;
  const int w    = tid >> 6;

  __shared__ _Float16 As[64 * 64];
  __shared__ _Float16 Bs[64 * 64];

  const int lr = lane >> 3;
  const int ls = (lane & 7) ^ lr;
  const size_t lbase = (size_t)ch * 1024 + ls * 8;
  const _Float16* gA = VT + (size_t)(bh * 64 + w * 16 + lr) * 4096 + lbase;
  const _Float16* gB = KT + (size_t)(bh * 64 + w * 16 + lr) * 4096 + lbase;
  _Float16* ldsA = As + (w * 16) * 64;
  _Float16* ldsB = Bs + (w * 16) * 64;

  half8 aones;
#pragma unroll
  for (int j = 0; j < 8; ++j) aones[j] = (lane & 15) == 0 ? (_Float16)1.0f : (_Float16)0.0f;

  f32x4 acc[5] = {};

  for (int k0 = 0; k0 < 1024; k0 += 64) {
    __syncthreads();
#pragma unroll
    for (int c = 0; c < 2; ++c) {
      GLD_LDS16(gA + k0 + (size_t)(c * 8) * 4096, ldsA + c * 8 * 64);
      GLD_LDS16(gB + k0 + (size_t)(c * 8) * 4096, ldsB + c * 8 * 64);
    }
    __syncthreads();

    half8 afr[4][2], bfr[2];
#pragma unroll
    for (int m = 0; m < 4; ++m)
#pragma unroll
      for (int kk = 0; kk < 2; ++kk) {
        int row  = m * 16 + (lane & 15);
        int byte = row * 128 + ((lane >> 4) << 4) + kk * 64;
        byte ^= (row & 7) << 4;
        afr[m][kk] = *(const half8*)((const char*)As + byte);
      }
#pragma unroll
    for (int kk = 0; kk < 2; ++kk) {
      int row  = w * 16 + (lane & 15);
      int byte = row * 128 + ((lane >> 4) << 4) + kk * 64;
      byte ^= (row & 7) << 4;
      bfr[kk] = *(const half8*)((const char*)Bs + byte);
    }
#pragma unroll
    for (int kk = 0; kk < 2; ++kk) {
#pragma unroll
      for (int m = 0; m < 4; ++m)
        acc[m] = __builtin_amdgcn_mfma_f32_16x16x32_f16(afr[m][kk], bfr[kk],
                                                        acc[m], 0, 0, 0);
      acc[4] = __builtin_amdgcn_mfma_f32_16x16x32_f16(aones, bfr[kk],
                                                      acc[4], 0, 0, 0);
    }
  }

  _Float16* outp = pKV + ((size_t)ch * 64 + bh) * 5120;
  const int col = w * 16 + (lane & 15);
#pragma unroll
  for (int m = 0; m < 5; ++m) {
#pragma unroll
    for (int i = 0; i < 4; ++i) {
      int row = m * 16 + ((lane >> 4) << 2) + i;
      outp[row * 64 + col] = (_Float16)acc[m][i];
    }
  }
}

// ---------------------------------------------------------------------------
__global__ __launch_bounds__(256)
void kv_combine(const _Float16* __restrict__ pKV, _Float16* __restrict__ KVTx) {
  int g = blockIdx.x * 256 + threadIdx.x;   // 0..327679
  int bh = g / 5120;
  int j  = g - bh * 5120;
  float s = 0.f;
#pragma unroll
  for (int ch = 0; ch < 4; ++ch)
    s += (float)pKV[((size_t)ch * 64 + bh) * 5120 + j];
  KVTx[(size_t)bh * 5120 + j] = (_Float16)s;
}

// ---------------------------------------------------------------------------
extern "C" void kernel_launch(void* const* d_in, const int* in_sizes, int n_in,
                              void* d_out, int out_size, void* d_ws, size_t ws_size,
                              hipStream_t stream) {
  const float* q  = (const float*)d_in[0];
  const float* k  = (const float*)d_in[1];
  const float* v  = (const float*)d_in[2];
  const float* wq = (const float*)d_in[3];
  const float* bq = (const float*)d_in[4];
  const float* wk = (const float*)d_in[5];
  const float* bk = (const float*)d_in[6];
  const float* wv = (const float*)d_in[7];
  const float* bv = (const float*)d_in[8];
  const float* wo = (const float*)d_in[9];
  const float* bo = (const float*)d_in[10];
  float* out = (float*)d_out;

  char* ws = (char*)d_ws;
  _Float16* Xk   = (_Float16*)(ws);                      // 0..32MB
  _Float16* KT   = (_Float16*)(ws + 33554432);           // 32..64MB
  _Float16* VT   = (_Float16*)(ws + 67108864);           // 64..96MB
  _Float16* pKV  = (_Float16*)(ws + 100663296);          // 2.62MB over whk/whv
  _Float16* whk  = (_Float16*)(ws + 100663296);          // 2MB (dies after K-gemm)
  _Float16* whv  = (_Float16*)(ws + 102760448);          // 2MB (dies after V-gemm)
  _Float16* whq  = (_Float16*)(ws + 104857600);          // 2MB
  _Float16* who  = (_Float16*)(ws + 106954752);          // 2MB (lives to the end)
  _Float16* KVTx = (_Float16*)(ws + 109051904);          // 655KB
  _Float16* att  = KT;                                   // reuse KT after KV built
  // d_out (64MB) as scratch until the final GEMM:
  _Float16* Xv   = (_Float16*)d_out;                     // 0..32MB of d_out
  _Float16* Xq   = (_Float16*)((char*)d_out + 33554432); // 32..64MB of d_out

  const int N8_BIG = MROWS * KDIM / 8;             // 2,097,152
  const int GBLK8  = (MROWS / 256) * (NDIM / 256); // 256 blocks

  // weights (fused small): 262,144 f4 -> (1024,4)
  cvt_w<<<dim3(1024, 4), 256, 0, stream>>>(wq, whq, wk, whk, wv, whv, wo, who);

  // k convert (standalone — nothing to overlap with)
  cvt_f32_to_f16<<<4096, 256, 0, stream>>>(k, Xk, N8_BIG);

  // K projection + fused v-convert tail (overlaps cvt with GEMM)
  gemm_8ph<1, 1, 1, _Float16><<<GBLK8, 512, 0, stream>>>(
      Xk, whk, bk, KT, nullptr, v, Xv);
  // V projection + fused q-convert tail
  gemm_8ph<0, 1, 1, _Float16><<<GBLK8, 512, 0, stream>>>(
      Xv, whv, bv, VT, nullptr, q, Xq);

  kv_mfma<<<dim3(64, 4), 256, 0, stream>>>(KT, VT, pKV);
  kv_combine<<<1280, 256, 0, stream>>>(pKV, KVTx);

  // Q projection + attention fused (8-phase + per-wave Ct epilogue)
  gemm_8ph<1, 2, 0, _Float16><<<GBLK8, 512, 0, stream>>>(
      Xq, whq, bq, att, KVTx, nullptr, nullptr);

  // output projection (8-phase, natural fp32) -> d_out (Xv/Xq dead)
  gemm_8ph<0, 0, 0, float><<<GBLK8, 512, 0, stream>>>(
      att, who, bo, out, nullptr, nullptr, nullptr);
}